// Round 6
// baseline (96.635 us; speedup 1.0000x reference)
//
#include <hip/hip_runtime.h>
#include <math.h>

namespace {

constexpr int RAD  = 6;
constexpr int P    = 13;
constexpr int NWIN = 169;   // P*P
constexpr int NTOT = 338;   // 2 refs * NWIN
constexpr int NCH  = 128;
constexpr int NCLS = 32;
constexpr int W    = 64;
constexpr int HW   = 4096;
constexpr float FOUR_LN2 = 2.772588722239781f;

// ---- kernel A tiling ----
constexpr int TX    = 32;            // pixels per block (half row)
constexpr int CHUNK = 4;             // channels per stage
constexpr int PW    = 48;            // patch width: 44 used + 4 pad
constexpr int PR    = 13;            // patch rows (dy)
constexpr int FRELEMS = CHUNK * PR * PW;   // 2496
constexpr int NCHUNK  = NCH / CHUNK;       // 32

__device__ __forceinline__ bool better(float va, int ia, float vb, int ib) {
  return (va > vb) || ((va == vb) && (ia < ib));
}

// ================= Kernel A: correlation volume =================
// grid: ((b*2+i)*64 + y)*2 + xh   (512 blocks), 256 threads
// waves 0-1: channels {0,1} of each 4-chunk; waves 2-3: channels {2,3}.
// vol layout: [b*2+i][m (169)][y][x]  (float)
__global__ __launch_bounds__(256, 4) void corr_kernel(
    const float* __restrict__ fr,   // [2][2][128][64][64]  (nref,b,c,y,x)
    const float* __restrict__ ft,   // [2][128][64][64]
    float* __restrict__ vol) {
  const int blk = blockIdx.x;
  const int xh = blk & 1;
  const int y  = (blk >> 1) & 63;
  const int bi = blk >> 7;             // b*2+i
  const int b  = bi >> 1;
  const int ii = bi & 1;
  const int x0 = xh * TX;
  const int t  = threadIdx.x;
  const int cg = t >> 7;               // channel group 0/1
  const int tl = t & 127;

  // smem: double-buffered fr patch (2*2496 floats), then aliased as the
  // 104*52-float reduction buffer after the K-loop's final barrier.
  __shared__ __align__(16) float smem[5408];
  __shared__ __align__(16) float ftbuf[2][CHUNK * TX];

  const int xg = tl & 7;               // x-quad within half row
  const int dy = tl >> 3;              // 0..12 valid when tl<104
  const bool comp = (tl < 104);

  // fr outer layout is [nref][b] -> index ii*2+b
  const float* frbase = fr + (size_t)((ii * 2 + b) * NCH) * HW;
  const float* ftbase = ft + (size_t)(b * NCH) * HW + y * W + x0;

  float acc[13][4];
  #pragma unroll
  for (int dx = 0; dx < 13; ++dx)
    #pragma unroll
    for (int k = 0; k < 4; ++k) acc[dx][k] = 0.f;

  float rg[10];
  float rft;

  // --- stage load: chunk starting at channel c0 -> registers ---
  auto stage_load = [&](int c0) {
    #pragma unroll
    for (int u = 0; u < 10; ++u) {
      const int e = t + u * 256;
      float v = 0.f;
      if (e < FRELEMS) {
        const int cc  = e / (PR * PW);
        const int rem = e - cc * (PR * PW);
        const int r   = rem / PW;
        const int xc  = rem - r * PW;
        const int yy  = y + r - RAD;
        const int xx  = x0 - RAD + xc;
        if ((unsigned)yy < 64u && (unsigned)xx < 64u && xc < 44)
          v = frbase[(size_t)(c0 + cc) * HW + yy * W + xx];
      }
      rg[u] = v;
    }
    if (t < 128) {
      const int cc = t >> 5;           // 0..3
      const int xl = t & 31;
      rft = ftbase[(size_t)(c0 + cc) * HW + xl];
    }
  };
  auto stage_write = [&](int s) {
    float* frb = smem + s * FRELEMS;
    #pragma unroll
    for (int u = 0; u < 10; ++u) {
      const int e = t + u * 256;
      if (e < FRELEMS) frb[e] = rg[u];
    }
    if (t < 128) ftbuf[s][t] = rft;
  };

  stage_load(0);
  stage_write(0);
  __syncthreads();

  for (int k = 0; k < NCHUNK; ++k) {
    const int cur = k & 1;
    if (k < NCHUNK - 1) stage_load((k + 1) * CHUNK);   // issue early
    if (comp) {
      const float* frb = smem + cur * FRELEMS;
      #pragma unroll
      for (int c2 = 0; c2 < 2; ++c2) {
        const int cc = cg * 2 + c2;
        const float* fp = frb + (cc * PR + dy) * PW + xg * 4;
        float w[16];
        #pragma unroll
        for (int j = 0; j < 4; ++j) {
          const float4 q4 = *(const float4*)(fp + 4 * j);
          w[4 * j] = q4.x; w[4 * j + 1] = q4.y; w[4 * j + 2] = q4.z; w[4 * j + 3] = q4.w;
        }
        const float4 tq = *(const float4*)(&ftbuf[cur][cc * TX + xg * 4]);
        const float tqa[4] = {tq.x, tq.y, tq.z, tq.w};
        #pragma unroll
        for (int dx = 0; dx < 13; ++dx)
          #pragma unroll
          for (int kk = 0; kk < 4; ++kk)
            acc[dx][kk] = fmaf(w[dx + kk], tqa[kk], acc[dx][kk]);
      }
    }
    __syncthreads();
    if (k < NCHUNK - 1) stage_write(cur ^ 1);
    __syncthreads();
  }

  // --- cross-channel-group reduction (smem aliased; staging is dead) ---
  if (comp && cg == 1) {
    float* rb = smem + tl * 52;
    #pragma unroll
    for (int dx = 0; dx < 13; ++dx)
      *(float4*)(rb + dx * 4) = make_float4(acc[dx][0], acc[dx][1], acc[dx][2], acc[dx][3]);
  }
  __syncthreads();
  if (comp && cg == 0) {
    const float* rb = smem + tl * 52;
    #pragma unroll
    for (int dx = 0; dx < 13; ++dx) {
      const float4 r = *(const float4*)(rb + dx * 4);
      acc[dx][0] += r.x; acc[dx][1] += r.y; acc[dx][2] += r.z; acc[dx][3] += r.w;
    }
    const int x4 = x0 + xg * 4;
    float* vp = vol + (size_t)(bi * NWIN + dy * 13) * HW + y * W + x4;
    #pragma unroll
    for (int dx = 0; dx < 13; ++dx) {
      float4 st = make_float4(acc[dx][0], acc[dx][1], acc[dx][2], acc[dx][3]);
      *(float4*)(vp + (size_t)dx * HW) = st;
    }
  }
}

// ================= Kernel B: softmax + top2 + heat + scatter =================
__global__ __launch_bounds__(384) void post_kernel(
    const float* __restrict__ vol,  // [2*2][169][64][64]
    const int*  __restrict__ q,     // [2][2][1][256][256]
    float* __restrict__ out) {      // [2][32][64][64]
  const int pix = blockIdx.x;          // b*4096 + y*64 + x
  const int b = pix >> 12;
  const int y = (pix >> 6) & 63;
  const int x = pix & 63;
  const int t = threadIdx.x;
  const int wid  = t >> 6;
  const int lane = t & 63;

  __shared__ float s[NTOT];
  __shared__ float wred[6];
  __shared__ float accS[NCLS];
  __shared__ float params[2][8];

  if (t < NCLS) accS[t] = 0.f;

  const bool act = (t < NTOT);
  const int i  = (t >= NWIN) ? 1 : 0;
  const int m  = t - i * NWIN;
  const int dy = m / P;
  const int dx = m - dy * P;
  const int yy = y + dy - RAD;
  const int xx = x + dx - RAD;
  const bool inb = ((unsigned)yy < 64u) && ((unsigned)xx < 64u);

  // ---------- phase 1: load correlation value ----------
  float dot = 0.f;
  if (act) dot = vol[(size_t)((b * 2 + i) * NWIN + m) * HW + y * W + x];

  // ---------- phase 2: joint softmax over 338 ----------
  const float v = act ? dot : -INFINITY;
  float lmax = v;
  for (int off = 32; off > 0; off >>= 1)
    lmax = fmaxf(lmax, __shfl_xor(lmax, off));
  if (lane == 0) wred[wid] = lmax;
  __syncthreads();
  const float gmax = fmaxf(fmaxf(fmaxf(wred[0], wred[1]), fmaxf(wred[2], wred[3])),
                           fmaxf(wred[4], wred[5]));
  const float e = act ? __expf(v - gmax) : 0.f;
  float lsum = e;
  for (int off = 32; off > 0; off >>= 1)
    lsum += __shfl_xor(lsum, off);
  __syncthreads();
  if (lane == 0) wred[wid] = lsum;
  __syncthreads();
  const float gsum = wred[0] + wred[1] + wred[2] + wred[3] + wred[4] + wred[5];
  const float prob = e / gsum;
  if (act) s[t] = prob;
  __syncthreads();

  // ---------- phase 3: per-ref top-2 (waves 0,1), stable tie-break ----------
  if (wid < 2) {
    const int ii = wid;
    float v1 = -1.f, v2 = -1.f;
    int i1 = 1 << 20, i2 = 1 << 20;
    for (int mm = lane; mm < NWIN; mm += 64) {
      const float pv = s[ii * NWIN + mm];
      if (better(pv, mm, v1, i1)) { v2 = v1; i2 = i1; v1 = pv; i1 = mm; }
      else if (better(pv, mm, v2, i2)) { v2 = pv; i2 = mm; }
    }
    for (int off = 32; off > 0; off >>= 1) {
      const float u1 = __shfl_xor(v1, off); const int j1 = __shfl_xor(i1, off);
      const float u2 = __shfl_xor(v2, off); const int j2 = __shfl_xor(i2, off);
      if (better(u1, j1, v1, i1)) {
        float nv2; int ni2;
        if (better(v1, i1, u2, j2)) { nv2 = v1; ni2 = i1; }
        else                        { nv2 = u2; ni2 = j2; }
        v1 = u1; i1 = j1; v2 = nv2; i2 = ni2;
      } else if (better(u1, j1, v2, i2)) {
        v2 = u1; i2 = j1;
      }
    }
    if (lane == 0) {
      const float e1 = __expf(v1);
      const float e2 = __expf(v2);
      const float rs = 1.f / (e1 + e2);
      params[ii][0] = (v1 > 0.1f) ? 1.f : 0.f;
      params[ii][1] = e1 * rs;
      params[ii][2] = (float)(i1 % P);
      params[ii][3] = (float)(i1 / P);
      params[ii][4] = e2 * rs;
      params[ii][5] = (float)(i2 % P);
      params[ii][6] = (float)(i2 / P);
    }
  }
  __syncthreads();

  // ---------- phase 4: corr2 + label scatter ----------
  if (act) {
    float val;
    if (params[i][0] != 0.f) {
      const float fdx0 = (float)dx - params[i][2];
      const float fdy0 = (float)dy - params[i][3];
      const float fdx1 = (float)dx - params[i][5];
      const float fdy1 = (float)dy - params[i][6];
      val = params[i][1] * __expf(-FOUR_LN2 * (fdx0 * fdx0 + fdy0 * fdy0))
          + params[i][4] * __expf(-FOUR_LN2 * (fdx1 * fdx1 + fdy1 * fdy1));
    } else {
      val = prob;
    }
    if (inb) {
      const int cls = q[(size_t)(i * 2 + b) * 65536 + (yy * 4) * 256 + (xx * 4)];
      atomicAdd(&accS[cls], val);
    }
  }
  __syncthreads();

  // ---------- phase 5: write output ----------
  if (t < NCLS) {
    const float sc = (t == 0) ? 1.0f : 1.15f;
    out[(size_t)(b * NCLS + t) * HW + (y * W + x)] = accS[t] * sc;
  }
}

}  // namespace

extern "C" void kernel_launch(void* const* d_in, const int* in_sizes, int n_in,
                              void* d_out, int out_size, void* d_ws, size_t ws_size,
                              hipStream_t stream) {
  const float* fr = (const float*)d_in[0];   // feats_r
  const float* ft = (const float*)d_in[1];   // feats_t
  const int*   q  = (const int*)d_in[2];     // quantized_r
  float* out = (float*)d_out;
  float* vol = (float*)d_ws;                 // 2*2*169*4096 floats = 11.1 MB

  corr_kernel<<<dim3(2 * 2 * 64 * 2), dim3(256), 0, stream>>>(fr, ft, vol);
  post_kernel<<<dim3(2 * HW), dim3(384), 0, stream>>>(vol, q, out);
}

// Round 7
// 73.754 us; speedup vs baseline: 1.3102x; 1.3102x over previous
//
#include <hip/hip_runtime.h>
#include <math.h>

namespace {

constexpr int RAD  = 6;
constexpr int P    = 13;
constexpr int NWIN = 169;   // P*P
constexpr int NTOT = 338;   // 2 refs * NWIN
constexpr int NCH  = 128;
constexpr int NCLS = 32;
constexpr int W    = 64;
constexpr int HW   = 4096;
constexpr float FOUR_LN2 = 2.772588722239781f;

// ---- kernel A tiling ----
constexpr int TX    = 32;            // pixels per block (half row)
constexpr int CHUNK = 8;             // channels per stage (16 chunks total)
constexpr int PW    = 48;            // patch width: 44 used + 4 pad
constexpr int PR    = 13;            // patch rows (dy)
constexpr int FRELEMS = CHUNK * PR * PW;   // 4992
constexpr int NCHUNK  = NCH / CHUNK;       // 16
constexpr int TILE    = TX * NWIN;         // 5408 floats

__device__ __forceinline__ bool better(float va, int ia, float vb, int ib) {
  return (va > vb) || ((va == vb) && (ia < ib));
}

// ================= Kernel A: correlation volume =================
// grid: ((b*2+i)*64 + y)*2 + xh   (512 blocks), 256 threads
// waves 0-1 (cg=0): channels 0-3 of each 8-chunk; waves 2-3 (cg=1): 4-7.
// vol layout: [pix][i][m]  (m innermost -> kernel B reads coalesced)
__global__ __launch_bounds__(256, 4) void corr_kernel(
    const float* __restrict__ fr,   // [2][2][128][64][64]  (nref,b,c,y,x)
    const float* __restrict__ ft,   // [2][128][64][64]
    float* __restrict__ vol) {
  const int blk = blockIdx.x;
  const int xh = blk & 1;
  const int y  = (blk >> 1) & 63;
  const int bi = blk >> 7;             // b*2+i
  const int b  = bi >> 1;
  const int ii = bi & 1;
  const int x0 = xh * TX;
  const int t  = threadIdx.x;
  const int cg = t >> 7;               // channel group 0/1
  const int tl = t & 127;

  // smem: double-buffered fr patch (2*4992 floats); after the K-loop the
  // first TILE (5408) floats are reused for partials and the output tile.
  __shared__ __align__(16) float smem[2 * FRELEMS];
  __shared__ __align__(16) float ftbuf[2][CHUNK * TX];

  const int xg = tl & 7;               // x-quad within half row
  const int dy = tl >> 3;              // 0..12 valid when tl<104
  const bool comp = (tl < 104);

  // fr outer layout is [nref][b] -> index ii*2+b
  const float* frbase = fr + (size_t)((ii * 2 + b) * NCH) * HW;
  const float* ftbase = ft + (size_t)(b * NCH) * HW + y * W + x0;

  float acc[13][4];
  #pragma unroll
  for (int dx = 0; dx < 13; ++dx)
    #pragma unroll
    for (int k = 0; k < 4; ++k) acc[dx][k] = 0.f;

  float rg[20];
  float rft;

  // --- stage load: chunk starting at channel c0 -> registers ---
  auto stage_load = [&](int c0) {
    #pragma unroll
    for (int u = 0; u < 20; ++u) {
      const int e = t + u * 256;
      float v = 0.f;
      if (e < FRELEMS) {
        const int cc  = e / (PR * PW);
        const int rem = e - cc * (PR * PW);
        const int r   = rem / PW;
        const int xc  = rem - r * PW;
        const int yy  = y + r - RAD;
        const int xx  = x0 - RAD + xc;
        if ((unsigned)yy < 64u && (unsigned)xx < 64u && xc < 44)
          v = frbase[(size_t)(c0 + cc) * HW + yy * W + xx];
      }
      rg[u] = v;
    }
    const int cc = t >> 5;             // 0..7
    const int xl = t & 31;
    rft = ftbase[(size_t)(c0 + cc) * HW + xl];
  };
  auto stage_write = [&](int s) {
    float* frb = smem + s * FRELEMS;
    #pragma unroll
    for (int u = 0; u < 20; ++u) {
      const int e = t + u * 256;
      if (e < FRELEMS) frb[e] = rg[u];
    }
    ftbuf[s][t] = rft;
  };

  stage_load(0);
  stage_write(0);
  __syncthreads();

  for (int k = 0; k < NCHUNK; ++k) {
    const int cur = k & 1;
    if (k < NCHUNK - 1) stage_load((k + 1) * CHUNK);   // issue early
    if (comp) {
      const float* frb = smem + cur * FRELEMS;
      #pragma unroll
      for (int c2 = 0; c2 < 4; ++c2) {
        const int cc = cg * 4 + c2;
        const float* fp = frb + (cc * PR + dy) * PW + xg * 4;
        float w[16];
        #pragma unroll
        for (int j = 0; j < 4; ++j) {
          const float4 q4 = *(const float4*)(fp + 4 * j);
          w[4 * j] = q4.x; w[4 * j + 1] = q4.y; w[4 * j + 2] = q4.z; w[4 * j + 3] = q4.w;
        }
        const float4 tq = *(const float4*)(&ftbuf[cur][cc * TX + xg * 4]);
        const float tqa[4] = {tq.x, tq.y, tq.z, tq.w};
        #pragma unroll
        for (int dx = 0; dx < 13; ++dx)
          #pragma unroll
          for (int kk = 0; kk < 4; ++kk)
            acc[dx][kk] = fmaf(w[dx + kk], tqa[kk], acc[dx][kk]);
      }
    }
    __syncthreads();
    if (k < NCHUNK - 1) stage_write(cur ^ 1);
    __syncthreads();
  }

  // --- cross-cg reduction (staging buffers dead now) ---
  if (comp && cg == 1) {
    float* rb = smem + tl * 52;                       // 208B stride, 16B aligned
    #pragma unroll
    for (int dx = 0; dx < 13; ++dx)
      *(float4*)(rb + dx * 4) = make_float4(acc[dx][0], acc[dx][1], acc[dx][2], acc[dx][3]);
  }
  __syncthreads();
  if (comp && cg == 0) {
    const float* rb = smem + tl * 52;
    #pragma unroll
    for (int dx = 0; dx < 13; ++dx) {
      const float4 r = *(const float4*)(rb + dx * 4);
      acc[dx][0] += r.x; acc[dx][1] += r.y; acc[dx][2] += r.z; acc[dx][3] += r.w;
    }
  }
  __syncthreads();
  // --- transpose to tile[x][m] in LDS, then contiguous store ---
  if (comp && cg == 0) {
    #pragma unroll
    for (int dx = 0; dx < 13; ++dx)
      #pragma unroll
      for (int kk = 0; kk < 4; ++kk)
        smem[(xg * 4 + kk) * NWIN + dy * 13 + dx] = acc[dx][kk];
  }
  __syncthreads();
  // vol[((b*4096 + y*64 + x) * 2 + ii) * 169 + m]; for x = x0..x0+31 the
  // block's span is NOT contiguous (stride 338 per x, 169 per half) -> store
  // per-element: e -> x = e/169, m = e%169.
  {
    float* gb = vol + ((size_t)(b * HW + y * W + x0) * 2 + ii) * NWIN;
    for (int u = 0; u < 22; ++u) {
      const int e = t + u * 256;
      if (e < TILE) {
        const int xl2 = e / NWIN;
        const int mm  = e - xl2 * NWIN;
        gb[(size_t)xl2 * (2 * NWIN) + mm] = smem[e];
      }
    }
  }
}

// ================= Kernel B: softmax + top2 + heat + scatter =================
__global__ __launch_bounds__(384) void post_kernel(
    const float* __restrict__ vol,  // [pix][2][169]
    const int*  __restrict__ q,     // [2][2][1][256][256]
    float* __restrict__ out) {      // [2][32][64][64]
  const int pix = blockIdx.x;          // b*4096 + y*64 + x
  const int b = pix >> 12;
  const int y = (pix >> 6) & 63;
  const int x = pix & 63;
  const int t = threadIdx.x;
  const int wid  = t >> 6;
  const int lane = t & 63;

  __shared__ float s[NTOT];
  __shared__ float wred[6];
  __shared__ float accS[NCLS];
  __shared__ float params[2][8];

  if (t < NCLS) accS[t] = 0.f;

  const bool act = (t < NTOT);
  const int i  = (t >= NWIN) ? 1 : 0;
  const int m  = t - i * NWIN;
  const int dy = m / P;
  const int dx = m - dy * P;
  const int yy = y + dy - RAD;
  const int xx = x + dx - RAD;
  const bool inb = ((unsigned)yy < 64u) && ((unsigned)xx < 64u);

  // ---------- phase 1: coalesced volume load ----------
  float dot = 0.f;
  if (act) dot = vol[(size_t)pix * NTOT + t];

  // ---------- phase 2: joint softmax over 338 ----------
  const float v = act ? dot : -INFINITY;
  float lmax = v;
  for (int off = 32; off > 0; off >>= 1)
    lmax = fmaxf(lmax, __shfl_xor(lmax, off));
  if (lane == 0) wred[wid] = lmax;
  __syncthreads();
  const float gmax = fmaxf(fmaxf(fmaxf(wred[0], wred[1]), fmaxf(wred[2], wred[3])),
                           fmaxf(wred[4], wred[5]));
  const float e = act ? __expf(v - gmax) : 0.f;
  float lsum = e;
  for (int off = 32; off > 0; off >>= 1)
    lsum += __shfl_xor(lsum, off);
  __syncthreads();
  if (lane == 0) wred[wid] = lsum;
  __syncthreads();
  const float gsum = wred[0] + wred[1] + wred[2] + wred[3] + wred[4] + wred[5];
  const float prob = e / gsum;
  if (act) s[t] = prob;
  __syncthreads();

  // ---------- phase 3: per-ref top-2 (waves 0,1), stable tie-break ----------
  if (wid < 2) {
    const int ii = wid;
    float v1 = -1.f, v2 = -1.f;
    int i1 = 1 << 20, i2 = 1 << 20;
    for (int mm = lane; mm < NWIN; mm += 64) {
      const float pv = s[ii * NWIN + mm];
      if (better(pv, mm, v1, i1)) { v2 = v1; i2 = i1; v1 = pv; i1 = mm; }
      else if (better(pv, mm, v2, i2)) { v2 = pv; i2 = mm; }
    }
    for (int off = 32; off > 0; off >>= 1) {
      const float u1 = __shfl_xor(v1, off); const int j1 = __shfl_xor(i1, off);
      const float u2 = __shfl_xor(v2, off); const int j2 = __shfl_xor(i2, off);
      if (better(u1, j1, v1, i1)) {
        float nv2; int ni2;
        if (better(v1, i1, u2, j2)) { nv2 = v1; ni2 = i1; }
        else                        { nv2 = u2; ni2 = j2; }
        v1 = u1; i1 = j1; v2 = nv2; i2 = ni2;
      } else if (better(u1, j1, v2, i2)) {
        v2 = u1; i2 = j1;
      }
    }
    if (lane == 0) {
      const float e1 = __expf(v1);
      const float e2 = __expf(v2);
      const float rs = 1.f / (e1 + e2);
      params[ii][0] = (v1 > 0.1f) ? 1.f : 0.f;
      params[ii][1] = e1 * rs;
      params[ii][2] = (float)(i1 % P);
      params[ii][3] = (float)(i1 / P);
      params[ii][4] = e2 * rs;
      params[ii][5] = (float)(i2 % P);
      params[ii][6] = (float)(i2 / P);
    }
  }
  __syncthreads();

  // ---------- phase 4: corr2 + label scatter ----------
  if (act) {
    float val;
    if (params[i][0] != 0.f) {
      const float fdx0 = (float)dx - params[i][2];
      const float fdy0 = (float)dy - params[i][3];
      const float fdx1 = (float)dx - params[i][5];
      const float fdy1 = (float)dy - params[i][6];
      val = params[i][1] * __expf(-FOUR_LN2 * (fdx0 * fdx0 + fdy0 * fdy0))
          + params[i][4] * __expf(-FOUR_LN2 * (fdx1 * fdx1 + fdy1 * fdy1));
    } else {
      val = prob;
    }
    if (inb) {
      const int cls = q[(size_t)(i * 2 + b) * 65536 + (yy * 4) * 256 + (xx * 4)];
      atomicAdd(&accS[cls], val);
    }
  }
  __syncthreads();

  // ---------- phase 5: write output ----------
  if (t < NCLS) {
    const float sc = (t == 0) ? 1.0f : 1.15f;
    out[(size_t)(b * NCLS + t) * HW + (y * W + x)] = accS[t] * sc;
  }
}

}  // namespace

extern "C" void kernel_launch(void* const* d_in, const int* in_sizes, int n_in,
                              void* d_out, int out_size, void* d_ws, size_t ws_size,
                              hipStream_t stream) {
  const float* fr = (const float*)d_in[0];   // feats_r
  const float* ft = (const float*)d_in[1];   // feats_t
  const int*   q  = (const int*)d_in[2];     // quantized_r
  float* out = (float*)d_out;
  float* vol = (float*)d_ws;                 // 2*4096*338 floats = 11.1 MB

  corr_kernel<<<dim3(2 * 2 * 64 * 2), dim3(256), 0, stream>>>(fr, ft, vol);
  post_kernel<<<dim3(2 * HW), dim3(384), 0, stream>>>(vol, q, out);
}

// Round 8
// 61.613 us; speedup vs baseline: 1.5684x; 1.1971x over previous
//
#include <hip/hip_runtime.h>
#include <math.h>

namespace {

constexpr int RAD  = 6;
constexpr int P    = 13;
constexpr int NWIN = 169;   // P*P
constexpr int NTOT = 338;   // 2 refs * NWIN
constexpr int NCH  = 128;
constexpr int NCLS = 32;
constexpr int W    = 64;
constexpr int HW   = 4096;
constexpr float FOUR_LN2 = 2.772588722239781f;

// ---- kernel A tiling ----
constexpr int TX    = 32;            // pixels per block (half row)
constexpr int CHUNK = 8;             // channels per stage (16 chunks total)
constexpr int PW    = 48;            // patch width: 44 used + 4 pad
constexpr int PR    = 13;            // patch rows (dy)
constexpr int FRELEMS = CHUNK * PR * PW;   // 4992
constexpr int NCHUNK  = NCH / CHUNK;       // 16
constexpr int TILE    = TX * NWIN;         // 5408 floats

__device__ __forceinline__ bool better(float va, int ia, float vb, int ib) {
  return (va > vb) || ((va == vb) && (ia < ib));
}

// ================= Kernel A: correlation volume =================
// (unchanged from R7 — proven)
__global__ __launch_bounds__(256, 4) void corr_kernel(
    const float* __restrict__ fr,   // [2][2][128][64][64]  (nref,b,c,y,x)
    const float* __restrict__ ft,   // [2][128][64][64]
    float* __restrict__ vol) {
  const int blk = blockIdx.x;
  const int xh = blk & 1;
  const int y  = (blk >> 1) & 63;
  const int bi = blk >> 7;             // b*2+i
  const int b  = bi >> 1;
  const int ii = bi & 1;
  const int x0 = xh * TX;
  const int t  = threadIdx.x;
  const int cg = t >> 7;               // channel group 0/1
  const int tl = t & 127;

  __shared__ __align__(16) float smem[2 * FRELEMS];
  __shared__ __align__(16) float ftbuf[2][CHUNK * TX];

  const int xg = tl & 7;               // x-quad within half row
  const int dy = tl >> 3;              // 0..12 valid when tl<104
  const bool comp = (tl < 104);

  const float* frbase = fr + (size_t)((ii * 2 + b) * NCH) * HW;
  const float* ftbase = ft + (size_t)(b * NCH) * HW + y * W + x0;

  float acc[13][4];
  #pragma unroll
  for (int dx = 0; dx < 13; ++dx)
    #pragma unroll
    for (int k = 0; k < 4; ++k) acc[dx][k] = 0.f;

  float rg[20];
  float rft;

  auto stage_load = [&](int c0) {
    #pragma unroll
    for (int u = 0; u < 20; ++u) {
      const int e = t + u * 256;
      float v = 0.f;
      if (e < FRELEMS) {
        const int cc  = e / (PR * PW);
        const int rem = e - cc * (PR * PW);
        const int r   = rem / PW;
        const int xc  = rem - r * PW;
        const int yy  = y + r - RAD;
        const int xx  = x0 - RAD + xc;
        if ((unsigned)yy < 64u && (unsigned)xx < 64u && xc < 44)
          v = frbase[(size_t)(c0 + cc) * HW + yy * W + xx];
      }
      rg[u] = v;
    }
    const int cc = t >> 5;             // 0..7
    const int xl = t & 31;
    rft = ftbase[(size_t)(c0 + cc) * HW + xl];
  };
  auto stage_write = [&](int s) {
    float* frb = smem + s * FRELEMS;
    #pragma unroll
    for (int u = 0; u < 20; ++u) {
      const int e = t + u * 256;
      if (e < FRELEMS) frb[e] = rg[u];
    }
    ftbuf[s][t] = rft;
  };

  stage_load(0);
  stage_write(0);
  __syncthreads();

  for (int k = 0; k < NCHUNK; ++k) {
    const int cur = k & 1;
    if (k < NCHUNK - 1) stage_load((k + 1) * CHUNK);
    if (comp) {
      const float* frb = smem + cur * FRELEMS;
      #pragma unroll
      for (int c2 = 0; c2 < 4; ++c2) {
        const int cc = cg * 4 + c2;
        const float* fp = frb + (cc * PR + dy) * PW + xg * 4;
        float w[16];
        #pragma unroll
        for (int j = 0; j < 4; ++j) {
          const float4 q4 = *(const float4*)(fp + 4 * j);
          w[4 * j] = q4.x; w[4 * j + 1] = q4.y; w[4 * j + 2] = q4.z; w[4 * j + 3] = q4.w;
        }
        const float4 tq = *(const float4*)(&ftbuf[cur][cc * TX + xg * 4]);
        const float tqa[4] = {tq.x, tq.y, tq.z, tq.w};
        #pragma unroll
        for (int dx = 0; dx < 13; ++dx)
          #pragma unroll
          for (int kk = 0; kk < 4; ++kk)
            acc[dx][kk] = fmaf(w[dx + kk], tqa[kk], acc[dx][kk]);
      }
    }
    __syncthreads();
    if (k < NCHUNK - 1) stage_write(cur ^ 1);
    __syncthreads();
  }

  if (comp && cg == 1) {
    float* rb = smem + tl * 52;
    #pragma unroll
    for (int dx = 0; dx < 13; ++dx)
      *(float4*)(rb + dx * 4) = make_float4(acc[dx][0], acc[dx][1], acc[dx][2], acc[dx][3]);
  }
  __syncthreads();
  if (comp && cg == 0) {
    const float* rb = smem + tl * 52;
    #pragma unroll
    for (int dx = 0; dx < 13; ++dx) {
      const float4 r = *(const float4*)(rb + dx * 4);
      acc[dx][0] += r.x; acc[dx][1] += r.y; acc[dx][2] += r.z; acc[dx][3] += r.w;
    }
  }
  __syncthreads();
  if (comp && cg == 0) {
    #pragma unroll
    for (int dx = 0; dx < 13; ++dx)
      #pragma unroll
      for (int kk = 0; kk < 4; ++kk)
        smem[(xg * 4 + kk) * NWIN + dy * 13 + dx] = acc[dx][kk];
  }
  __syncthreads();
  {
    float* gb = vol + ((size_t)(b * HW + y * W + x0) * 2 + ii) * NWIN;
    for (int u = 0; u < 22; ++u) {
      const int e = t + u * 256;
      if (e < TILE) {
        const int xl2 = e / NWIN;
        const int mm  = e - xl2 * NWIN;
        gb[(size_t)xl2 * (2 * NWIN) + mm] = smem[e];
      }
    }
  }
}

// ================= Kernel L: dense down-sampled label map =================
// lab[(i*2+b)*4096 + yy*64 + xx] = q[(i*2+b)*65536 + yy*4*256 + xx*4]
__global__ __launch_bounds__(256) void lab_kernel(
    const int* __restrict__ q, int* __restrict__ lab) {
  const int idx = blockIdx.x * 256 + threadIdx.x;   // 0..16383
  const int i2b = idx >> 12;
  const int rem = idx & 4095;
  const int yy  = rem >> 6;
  const int xx  = rem & 63;
  lab[idx] = q[(size_t)i2b * 65536 + (yy * 4) * 256 + xx * 4];
}

// ================= Kernel B: wave-per-pixel post-processing =================
// grid 2048 x 256 threads; wave w handles pixel blk*4+w (4 consecutive x).
__global__ __launch_bounds__(256) void post_kernel(
    const float* __restrict__ vol,  // [pix][2][169]
    const int*  __restrict__ lab,   // [4][64][64]
    float* __restrict__ out) {      // [2][32][64][64]
  const int blk  = blockIdx.x;
  const int t    = threadIdx.x;
  const int w    = t >> 6;
  const int lane = t & 63;
  const int pix  = blk * 4 + w;
  const int b = pix >> 12;
  const int y = (pix >> 6) & 63;
  const int x = pix & 63;

  __shared__ float accS[4][NCLS];
  accS[w][lane & 31] = 0.f;       // each wave zeroes its own slice (both halves write same 0)

  // ---- load 6 strided elements, find max ----
  float vv[6];
  float lmax = -INFINITY;
  const float* vp = vol + (size_t)pix * NTOT;
  #pragma unroll
  for (int k = 0; k < 6; ++k) {
    const int e = lane + 64 * k;
    vv[k] = (e < NTOT) ? vp[e] : -INFINITY;
    lmax = fmaxf(lmax, vv[k]);
  }
  #pragma unroll
  for (int off = 32; off > 0; off >>= 1)
    lmax = fmaxf(lmax, __shfl_xor(lmax, off));

  // ---- exp + sum ----
  float p[6];
  float lsum = 0.f;
  #pragma unroll
  for (int k = 0; k < 6; ++k) {
    const int e = lane + 64 * k;
    p[k] = (e < NTOT) ? __expf(vv[k] - lmax) : 0.f;
    lsum += p[k];
  }
  #pragma unroll
  for (int off = 32; off > 0; off >>= 1)
    lsum += __shfl_xor(lsum, off);
  const float rinv = 1.f / lsum;
  #pragma unroll
  for (int k = 0; k < 6; ++k) p[k] *= rinv;   // normalized probs

  // ---- per-lane top-2 for each ref ----
  float a1_0 = -1.f, a2_0 = -1.f, a1_1 = -1.f, a2_1 = -1.f;
  int   j1_0 = 1 << 20, j2_0 = 1 << 20, j1_1 = 1 << 20, j2_1 = 1 << 20;
  #pragma unroll
  for (int k = 0; k < 6; ++k) {
    const int e = lane + 64 * k;
    if (e < NTOT) {
      const int r = (e >= NWIN) ? 1 : 0;
      const int m = e - r * NWIN;
      const float pv = p[k];
      if (r == 0) {
        if (better(pv, m, a1_0, j1_0)) { a2_0 = a1_0; j2_0 = j1_0; a1_0 = pv; j1_0 = m; }
        else if (better(pv, m, a2_0, j2_0)) { a2_0 = pv; j2_0 = m; }
      } else {
        if (better(pv, m, a1_1, j1_1)) { a2_1 = a1_1; j2_1 = j1_1; a1_1 = pv; j1_1 = m; }
        else if (better(pv, m, a2_1, j2_1)) { a2_1 = pv; j2_1 = m; }
      }
    }
  }
  // ---- butterfly merge: all lanes end with the wave-wide top-2 (both refs) ----
  #pragma unroll
  for (int off = 32; off > 0; off >>= 1) {
    {
      const float u1 = __shfl_xor(a1_0, off); const int q1 = __shfl_xor(j1_0, off);
      const float u2 = __shfl_xor(a2_0, off); const int q2 = __shfl_xor(j2_0, off);
      if (better(u1, q1, a1_0, j1_0)) {
        float nv2; int ni2;
        if (better(a1_0, j1_0, u2, q2)) { nv2 = a1_0; ni2 = j1_0; }
        else                            { nv2 = u2;   ni2 = q2; }
        a1_0 = u1; j1_0 = q1; a2_0 = nv2; j2_0 = ni2;
      } else if (better(u1, q1, a2_0, j2_0)) { a2_0 = u1; j2_0 = q1; }
    }
    {
      const float u1 = __shfl_xor(a1_1, off); const int q1 = __shfl_xor(j1_1, off);
      const float u2 = __shfl_xor(a2_1, off); const int q2 = __shfl_xor(j2_1, off);
      if (better(u1, q1, a1_1, j1_1)) {
        float nv2; int ni2;
        if (better(a1_1, j1_1, u2, q2)) { nv2 = a1_1; ni2 = j1_1; }
        else                            { nv2 = u2;   ni2 = q2; }
        a1_1 = u1; j1_1 = q1; a2_1 = nv2; j2_1 = ni2;
      } else if (better(u1, q1, a2_1, j2_1)) { a2_1 = u1; j2_1 = q1; }
    }
  }

  // ---- per-ref heat params (every lane computes identically) ----
  const float e10 = __expf(a1_0), e20 = __expf(a2_0);
  const float rs0 = 1.f / (e10 + e20);
  const float w00 = e10 * rs0, w10 = e20 * rs0;
  const bool  fl0 = (a1_0 > 0.1f);
  const float xs00 = (float)(j1_0 % P), ys00 = (float)(j1_0 / P);
  const float xs10 = (float)(j2_0 % P), ys10 = (float)(j2_0 / P);

  const float e11 = __expf(a1_1), e21 = __expf(a2_1);
  const float rs1 = 1.f / (e11 + e21);
  const float w01 = e11 * rs1, w11 = e21 * rs1;
  const bool  fl1 = (a1_1 > 0.1f);
  const float xs01 = (float)(j1_1 % P), ys01 = (float)(j1_1 / P);
  const float xs11 = (float)(j2_1 % P), ys11 = (float)(j2_1 / P);

  // ---- phase 4: corr2 value + label scatter into wave-private bins ----
  #pragma unroll
  for (int k = 0; k < 6; ++k) {
    const int e = lane + 64 * k;
    if (e < NTOT) {
      const int r  = (e >= NWIN) ? 1 : 0;
      const int m  = e - r * NWIN;
      const int dy = m / P;
      const int dx = m - dy * P;
      const bool  fl = r ? fl1 : fl0;
      float val;
      if (fl) {
        const float wA = r ? w01 : w00, wB = r ? w11 : w10;
        const float xA = r ? xs01 : xs00, yA = r ? ys01 : ys00;
        const float xB = r ? xs11 : xs10, yB = r ? ys11 : ys10;
        const float fdx0 = (float)dx - xA, fdy0 = (float)dy - yA;
        const float fdx1 = (float)dx - xB, fdy1 = (float)dy - yB;
        val = wA * __expf(-FOUR_LN2 * (fdx0 * fdx0 + fdy0 * fdy0))
            + wB * __expf(-FOUR_LN2 * (fdx1 * fdx1 + fdy1 * fdy1));
      } else {
        val = p[k];
      }
      const int yy = y + dy - RAD;
      const int xx = x + dx - RAD;
      if ((unsigned)yy < 64u && (unsigned)xx < 64u) {
        const int cls = lab[(size_t)(r * 2 + b) * 4096 + yy * W + xx];
        atomicAdd(&accS[w][cls], val);
      }
    }
  }
  __syncthreads();

  // ---- output: 4 consecutive pixels, 16B per class ----
  if (t < 4 * NCLS) {
    const int cls = t >> 2;
    const int j   = t & 3;
    const int x0  = (blk * 4) & 63;
    const float sc = (cls == 0) ? 1.0f : 1.15f;
    out[(size_t)(b * NCLS + cls) * HW + y * W + x0 + j] = accS[j][cls] * sc;
  }
}

}  // namespace

extern "C" void kernel_launch(void* const* d_in, const int* in_sizes, int n_in,
                              void* d_out, int out_size, void* d_ws, size_t ws_size,
                              hipStream_t stream) {
  const float* fr = (const float*)d_in[0];   // feats_r
  const float* ft = (const float*)d_in[1];   // feats_t
  const int*   q  = (const int*)d_in[2];     // quantized_r
  float* out = (float*)d_out;
  float* vol = (float*)d_ws;                             // 11,075,584 B
  int*   lab = (int*)((char*)d_ws + (size_t)2 * HW * NTOT * sizeof(float)); // +64 KB

  lab_kernel<<<dim3(64), dim3(256), 0, stream>>>(q, lab);
  corr_kernel<<<dim3(2 * 2 * 64 * 2), dim3(256), 0, stream>>>(fr, ft, vol);
  post_kernel<<<dim3(2 * HW / 4), dim3(256), 0, stream>>>(vol, lab, out);
}

// Round 9
// 60.882 us; speedup vs baseline: 1.5873x; 1.0120x over previous
//
#include <hip/hip_runtime.h>
#include <math.h>

namespace {

constexpr int RAD  = 6;
constexpr int P    = 13;
constexpr int NWIN = 169;   // P*P
constexpr int NTOT = 338;   // 2 refs * NWIN
constexpr int NCH  = 128;
constexpr int NCLS = 32;
constexpr int W    = 64;
constexpr int HW   = 4096;
constexpr float FOUR_LN2 = 2.772588722239781f;

// ---- kernel A tiling ----
constexpr int TX    = 32;            // pixels per block (half row)
constexpr int CHUNK = 8;             // channels per stage (16 chunks total)
constexpr int PW    = 48;            // patch width: 44 used + 4 pad
constexpr int PR    = 13;            // patch rows (dy)
constexpr int FRELEMS = CHUNK * PR * PW;   // 4992
constexpr int NCHUNK  = NCH / CHUNK;       // 16
constexpr int TILE    = TX * NWIN;         // 5408 floats

__device__ __forceinline__ bool better(float va, int ia, float vb, int ib) {
  return (va > vb) || ((va == vb) && (ia < ib));
}

// ================= Kernel A: correlation volume =================
// grid: ((b*2+i)*64 + y)*2 + xh   (512 blocks), 256 threads
// Staging addresses hoisted out of the chunk loop (loop-invariant).
__global__ __launch_bounds__(256, 2) void corr_kernel(
    const float* __restrict__ fr,   // [2][2][128][64][64]  (nref,b,c,y,x)
    const float* __restrict__ ft,   // [2][128][64][64]
    float* __restrict__ vol) {
  const int blk = blockIdx.x;
  const int xh = blk & 1;
  const int y  = (blk >> 1) & 63;
  const int bi = blk >> 7;             // b*2+i
  const int b  = bi >> 1;
  const int ii = bi & 1;
  const int x0 = xh * TX;
  const int t  = threadIdx.x;
  const int cg = t >> 7;               // channel group 0/1
  const int tl = t & 127;

  __shared__ __align__(16) float smem[2 * FRELEMS];
  __shared__ __align__(16) float ftbuf[2][CHUNK * TX];

  const int xg = tl & 7;               // x-quad within half row
  const int dy = tl >> 3;              // 0..12 valid when tl<104
  const bool comp = (tl < 104);

  const float* frbase = fr + (size_t)((ii * 2 + b) * NCH) * HW;
  // ft lane address: channel (t>>5), pixel x0+(t&31); bumped by c0*HW per chunk
  const float* ftp = ft + (size_t)(b * NCH + (t >> 5)) * HW + y * W + x0 + (t & 31);

  // ---- hoisted staging addresses (loop-invariant across chunks) ----
  int offc[20];
  unsigned vmsk = 0u;
  #pragma unroll
  for (int u = 0; u < 20; ++u) {
    const int e = t + u * 256;
    int o = 0;
    if (e < FRELEMS) {
      const int cc  = e / (PR * PW);
      const int rem = e - cc * (PR * PW);
      const int r   = rem / PW;
      const int xc  = rem - r * PW;
      const int yy  = y + r - RAD;
      const int xx  = x0 - RAD + xc;
      if ((unsigned)yy < 64u && (unsigned)xx < 64u && xc < 44) {
        o = cc * HW + yy * W + xx;
        vmsk |= (1u << u);
      }
    }
    offc[u] = o;
  }

  float acc[13][4];
  #pragma unroll
  for (int dx = 0; dx < 13; ++dx)
    #pragma unroll
    for (int k = 0; k < 4; ++k) acc[dx][k] = 0.f;

  float rg[20];
  float rft;

  auto stage_load = [&](int c0) {
    const float* fb = frbase + (size_t)c0 * HW;
    #pragma unroll
    for (int u = 0; u < 20; ++u) {
      const float v = fb[offc[u]];
      rg[u] = (vmsk & (1u << u)) ? v : 0.f;
    }
    rft = ftp[(size_t)c0 * HW];
  };
  auto stage_write = [&](int s) {
    float* frb = smem + s * FRELEMS;
    #pragma unroll
    for (int u = 0; u < 20; ++u) {
      const int e = t + u * 256;
      if (e < FRELEMS) frb[e] = rg[u];
    }
    ftbuf[s][t] = rft;
  };

  stage_load(0);
  stage_write(0);
  __syncthreads();

  for (int k = 0; k < NCHUNK; ++k) {
    const int cur = k & 1;
    if (k < NCHUNK - 1) stage_load((k + 1) * CHUNK);
    if (comp) {
      const float* frb = smem + cur * FRELEMS;
      #pragma unroll
      for (int c2 = 0; c2 < 4; ++c2) {
        const int cc = cg * 4 + c2;
        const float* fp = frb + (cc * PR + dy) * PW + xg * 4;
        float w[16];
        #pragma unroll
        for (int j = 0; j < 4; ++j) {
          const float4 q4 = *(const float4*)(fp + 4 * j);
          w[4 * j] = q4.x; w[4 * j + 1] = q4.y; w[4 * j + 2] = q4.z; w[4 * j + 3] = q4.w;
        }
        const float4 tq = *(const float4*)(&ftbuf[cur][cc * TX + xg * 4]);
        const float tqa[4] = {tq.x, tq.y, tq.z, tq.w};
        #pragma unroll
        for (int dx = 0; dx < 13; ++dx)
          #pragma unroll
          for (int kk = 0; kk < 4; ++kk)
            acc[dx][kk] = fmaf(w[dx + kk], tqa[kk], acc[dx][kk]);
      }
    }
    __syncthreads();
    if (k < NCHUNK - 1) stage_write(cur ^ 1);
    __syncthreads();
  }

  if (comp && cg == 1) {
    float* rb = smem + tl * 52;
    #pragma unroll
    for (int dx = 0; dx < 13; ++dx)
      *(float4*)(rb + dx * 4) = make_float4(acc[dx][0], acc[dx][1], acc[dx][2], acc[dx][3]);
  }
  __syncthreads();
  if (comp && cg == 0) {
    const float* rb = smem + tl * 52;
    #pragma unroll
    for (int dx = 0; dx < 13; ++dx) {
      const float4 r = *(const float4*)(rb + dx * 4);
      acc[dx][0] += r.x; acc[dx][1] += r.y; acc[dx][2] += r.z; acc[dx][3] += r.w;
    }
  }
  __syncthreads();
  if (comp && cg == 0) {
    #pragma unroll
    for (int dx = 0; dx < 13; ++dx)
      #pragma unroll
      for (int kk = 0; kk < 4; ++kk)
        smem[(xg * 4 + kk) * NWIN + dy * 13 + dx] = acc[dx][kk];
  }
  __syncthreads();
  {
    float* gb = vol + ((size_t)(b * HW + y * W + x0) * 2 + ii) * NWIN;
    for (int u = 0; u < 22; ++u) {
      const int e = t + u * 256;
      if (e < TILE) {
        const int xl2 = e / NWIN;
        const int mm  = e - xl2 * NWIN;
        gb[(size_t)xl2 * (2 * NWIN) + mm] = smem[e];
      }
    }
  }
}

// ================= Kernel L: dense down-sampled label map =================
__global__ __launch_bounds__(256) void lab_kernel(
    const int* __restrict__ q, int* __restrict__ lab) {
  const int idx = blockIdx.x * 256 + threadIdx.x;   // 0..16383
  const int i2b = idx >> 12;
  const int rem = idx & 4095;
  const int yy  = rem >> 6;
  const int xx  = rem & 63;
  lab[idx] = q[(size_t)i2b * 65536 + (yy * 4) * 256 + xx * 4];
}

// ================= Kernel B: wave-per-pixel post-processing =================
__global__ __launch_bounds__(256) void post_kernel(
    const float* __restrict__ vol,  // [pix][2][169]
    const int*  __restrict__ lab,   // [4][64][64]
    float* __restrict__ out) {      // [2][32][64][64]
  const int blk  = blockIdx.x;
  const int t    = threadIdx.x;
  const int w    = t >> 6;
  const int lane = t & 63;
  const int pix  = blk * 4 + w;
  const int b = pix >> 12;
  const int y = (pix >> 6) & 63;
  const int x = pix & 63;

  __shared__ float accS[4][NCLS];
  accS[w][lane & 31] = 0.f;

  float vv[6];
  float lmax = -INFINITY;
  const float* vp = vol + (size_t)pix * NTOT;
  #pragma unroll
  for (int k = 0; k < 6; ++k) {
    const int e = lane + 64 * k;
    vv[k] = (e < NTOT) ? vp[e] : -INFINITY;
    lmax = fmaxf(lmax, vv[k]);
  }
  #pragma unroll
  for (int off = 32; off > 0; off >>= 1)
    lmax = fmaxf(lmax, __shfl_xor(lmax, off));

  float p[6];
  float lsum = 0.f;
  #pragma unroll
  for (int k = 0; k < 6; ++k) {
    const int e = lane + 64 * k;
    p[k] = (e < NTOT) ? __expf(vv[k] - lmax) : 0.f;
    lsum += p[k];
  }
  #pragma unroll
  for (int off = 32; off > 0; off >>= 1)
    lsum += __shfl_xor(lsum, off);
  const float rinv = 1.f / lsum;
  #pragma unroll
  for (int k = 0; k < 6; ++k) p[k] *= rinv;

  float a1_0 = -1.f, a2_0 = -1.f, a1_1 = -1.f, a2_1 = -1.f;
  int   j1_0 = 1 << 20, j2_0 = 1 << 20, j1_1 = 1 << 20, j2_1 = 1 << 20;
  #pragma unroll
  for (int k = 0; k < 6; ++k) {
    const int e = lane + 64 * k;
    if (e < NTOT) {
      const int r = (e >= NWIN) ? 1 : 0;
      const int m = e - r * NWIN;
      const float pv = p[k];
      if (r == 0) {
        if (better(pv, m, a1_0, j1_0)) { a2_0 = a1_0; j2_0 = j1_0; a1_0 = pv; j1_0 = m; }
        else if (better(pv, m, a2_0, j2_0)) { a2_0 = pv; j2_0 = m; }
      } else {
        if (better(pv, m, a1_1, j1_1)) { a2_1 = a1_1; j2_1 = j1_1; a1_1 = pv; j1_1 = m; }
        else if (better(pv, m, a2_1, j2_1)) { a2_1 = pv; j2_1 = m; }
      }
    }
  }
  #pragma unroll
  for (int off = 32; off > 0; off >>= 1) {
    {
      const float u1 = __shfl_xor(a1_0, off); const int q1 = __shfl_xor(j1_0, off);
      const float u2 = __shfl_xor(a2_0, off); const int q2 = __shfl_xor(j2_0, off);
      if (better(u1, q1, a1_0, j1_0)) {
        float nv2; int ni2;
        if (better(a1_0, j1_0, u2, q2)) { nv2 = a1_0; ni2 = j1_0; }
        else                            { nv2 = u2;   ni2 = q2; }
        a1_0 = u1; j1_0 = q1; a2_0 = nv2; j2_0 = ni2;
      } else if (better(u1, q1, a2_0, j2_0)) { a2_0 = u1; j2_0 = q1; }
    }
    {
      const float u1 = __shfl_xor(a1_1, off); const int q1 = __shfl_xor(j1_1, off);
      const float u2 = __shfl_xor(a2_1, off); const int q2 = __shfl_xor(j2_1, off);
      if (better(u1, q1, a1_1, j1_1)) {
        float nv2; int ni2;
        if (better(a1_1, j1_1, u2, q2)) { nv2 = a1_1; ni2 = j1_1; }
        else                            { nv2 = u2;   ni2 = q2; }
        a1_1 = u1; j1_1 = q1; a2_1 = nv2; j2_1 = ni2;
      } else if (better(u1, q1, a2_1, j2_1)) { a2_1 = u1; j2_1 = q1; }
    }
  }

  const float e10 = __expf(a1_0), e20 = __expf(a2_0);
  const float rs0 = 1.f / (e10 + e20);
  const float w00 = e10 * rs0, w10 = e20 * rs0;
  const bool  fl0 = (a1_0 > 0.1f);
  const float xs00 = (float)(j1_0 % P), ys00 = (float)(j1_0 / P);
  const float xs10 = (float)(j2_0 % P), ys10 = (float)(j2_0 / P);

  const float e11 = __expf(a1_1), e21 = __expf(a2_1);
  const float rs1 = 1.f / (e11 + e21);
  const float w01 = e11 * rs1, w11 = e21 * rs1;
  const bool  fl1 = (a1_1 > 0.1f);
  const float xs01 = (float)(j1_1 % P), ys01 = (float)(j1_1 / P);
  const float xs11 = (float)(j2_1 % P), ys11 = (float)(j2_1 / P);

  #pragma unroll
  for (int k = 0; k < 6; ++k) {
    const int e = lane + 64 * k;
    if (e < NTOT) {
      const int r  = (e >= NWIN) ? 1 : 0;
      const int m  = e - r * NWIN;
      const int dy = m / P;
      const int dx = m - dy * P;
      const bool  fl = r ? fl1 : fl0;
      float val;
      if (fl) {
        const float wA = r ? w01 : w00, wB = r ? w11 : w10;
        const float xA = r ? xs01 : xs00, yA = r ? ys01 : ys00;
        const float xB = r ? xs11 : xs10, yB = r ? ys11 : ys10;
        const float fdx0 = (float)dx - xA, fdy0 = (float)dy - yA;
        const float fdx1 = (float)dx - xB, fdy1 = (float)dy - yB;
        val = wA * __expf(-FOUR_LN2 * (fdx0 * fdx0 + fdy0 * fdy0))
            + wB * __expf(-FOUR_LN2 * (fdx1 * fdx1 + fdy1 * fdy1));
      } else {
        val = p[k];
      }
      const int yy = y + dy - RAD;
      const int xx = x + dx - RAD;
      if ((unsigned)yy < 64u && (unsigned)xx < 64u) {
        const int cls = lab[(size_t)(r * 2 + b) * 4096 + yy * W + xx];
        atomicAdd(&accS[w][cls], val);
      }
    }
  }
  __syncthreads();

  if (t < 4 * NCLS) {
    const int cls = t >> 2;
    const int j   = t & 3;
    const int x0  = (blk * 4) & 63;
    const float sc = (cls == 0) ? 1.0f : 1.15f;
    out[(size_t)(b * NCLS + cls) * HW + y * W + x0 + j] = accS[j][cls] * sc;
  }
}

}  // namespace

extern "C" void kernel_launch(void* const* d_in, const int* in_sizes, int n_in,
                              void* d_out, int out_size, void* d_ws, size_t ws_size,
                              hipStream_t stream) {
  const float* fr = (const float*)d_in[0];   // feats_r
  const float* ft = (const float*)d_in[1];   // feats_t
  const int*   q  = (const int*)d_in[2];     // quantized_r
  float* out = (float*)d_out;
  float* vol = (float*)d_ws;                             // 11,075,584 B
  int*   lab = (int*)((char*)d_ws + (size_t)2 * HW * NTOT * sizeof(float)); // +64 KB

  lab_kernel<<<dim3(64), dim3(256), 0, stream>>>(q, lab);
  corr_kernel<<<dim3(2 * 2 * 64 * 2), dim3(256), 0, stream>>>(fr, ft, vol);
  post_kernel<<<dim3(2 * HW / 4), dim3(256), 0, stream>>>(vol, lab, out);
}